// Round 4
// baseline (90.044 us; speedup 1.0000x reference)
//
#include <hip/hip_runtime.h>
#include <hip/hip_bf16.h>

// Problem constants
#define B_  2
#define L_  2048
#define C_  1024
#define H_  16
#define K_  32
#define DH_ 64
#define M_  (B_ * L_)   // 4096 rows in all GEMMs

typedef __hip_bfloat16 bf16;
typedef __attribute__((ext_vector_type(4))) float f32x4;
typedef __attribute__((ext_vector_type(8))) short short8;
typedef __attribute__((ext_vector_type(8))) unsigned short u16x8;

__device__ inline unsigned short f2bf(float f) {
    __hip_bfloat16 h = __float2bfloat16(f);  // RTN
    return *reinterpret_cast<unsigned short*>(&h);
}
__device__ inline float bf2f(unsigned short u) {
    return __uint_as_float(((unsigned)u) << 16);
}
__device__ inline void gld_lds16(const bf16* g, bf16* l) {
    __builtin_amdgcn_global_load_lds(
        (const __attribute__((address_space(1))) void*)g,
        (__attribute__((address_space(3))) void*)l,
        16, 0, 0);
}

// ---------------------------------------------------------------------------
// Kernel 1: convert x, Wq, Wk, Wv, Wo from f32 to bf16 (one fused launch).
// ---------------------------------------------------------------------------
__global__ void __launch_bounds__(256) cvt_all(
    const float* __restrict__ x,  const float* __restrict__ wq,
    const float* __restrict__ wk, const float* __restrict__ wv,
    const float* __restrict__ wo,
    bf16* __restrict__ xb,  bf16* __restrict__ wqb, bf16* __restrict__ wkb,
    bf16* __restrict__ wvb, bf16* __restrict__ wob)
{
    int g = blockIdx.x * 256 + threadIdx.x;
    const float* src; bf16* dst; int o;
    if (g < 1048576)      { src = x;  dst = xb;  o = g; }
    else if (g < 1310720) { src = wq; dst = wqb; o = g - 1048576; }
    else if (g < 1572864) { src = wk; dst = wkb; o = g - 1310720; }
    else if (g < 1835008) { src = wv; dst = wvb; o = g - 1572864; }
    else                  { src = wo; dst = wob; o = g - 1835008; }
    float4 f = reinterpret_cast<const float4*>(src)[o];
    ushort4 u;
    u.x = f2bf(f.x); u.y = f2bf(f.y); u.z = f2bf(f.z); u.w = f2bf(f.w);
    reinterpret_cast<ushort4*>(dst)[o] = u;
}

// ---------------------------------------------------------------------------
// Kernel 2: 8-phase 256x256 QKV GEMM (T2+T3+T4+T5).  Y = x @ [Wq|Wk|Wv]^T.
// M=4096, N=3072, K=1024.  BM=BN=256, BK=64, 512 threads = 8 waves (2M x 4N),
// per-wave C = 128x64.  LDS 128 KiB: [buf][A/B][khalf][256 rows][4 x 16B].
// Half-tiles staged in consumption order (A-kh0, B-kh0, A-kh1, B-kh1);
// counted s_waitcnt vmcnt(4) twice per K-tile (never 0 mid-loop); 2 barriers
// per K-tile; 16 MFMA per phase under setprio.  Swizzle: chunk ^= (row>>1)&3
// applied on the global source (stage) and on ds_read — LDS stays linear.
// ---------------------------------------------------------------------------
struct Gemm8Args {
    const bf16* A;
    const bf16* W[3];
    bf16* Y[3];
    float scale0;
};

#define SM_(buf, ab, kh, row, ch) sm[(buf)][(ab)][(kh)][(row)][(ch)]

#define STAGE(bufn, ab, kh, rh, kt) {                                        \
    const bf16* gb_ = ((ab) == 0)                                            \
        ? A + (size_t)(m0 + (rh) * 128) * 1024                               \
        : W + (size_t)(nw0 + (rh) * 128) * 1024;                             \
    const bf16* src_ = gb_ + (size_t)srow * 1024 + (kt) * 64 + (kh) * 32     \
                       + scc * 8;                                            \
    bf16* lb_ = (bf16*)&SM_((bufn), (ab), (kh), (rh) * 128, 0)               \
                + (size_t)(tid & ~63) * 8;                                   \
    gld_lds16(src_, lb_);                                                    \
}

#define RD_A(cur, qm, kh) {                                                  \
    _Pragma("unroll")                                                        \
    for (int mf = 0; mf < 4; ++mf) {                                         \
        const int R_  = wm * 128 + (qm) * 64 + mf * 16 + (lane & 15);        \
        const int ch_ = (lane >> 4) ^ ((R_ >> 1) & 3);                       \
        ak[mf] = SM_((cur), 0, (kh), R_, ch_);                               \
    }                                                                        \
}

#define RD_B(cur, kh) {                                                      \
    _Pragma("unroll")                                                        \
    for (int nf = 0; nf < 4; ++nf) {                                         \
        const int R_  = wn * 64 + nf * 16 + (lane & 15);                     \
        const int ch_ = (lane >> 4) ^ ((R_ >> 1) & 3);                       \
        bk[nf] = SM_((cur), 1, (kh), R_, ch_);                               \
    }                                                                        \
}

#define MAC16(qm) {                                                          \
    __builtin_amdgcn_s_setprio(1);                                           \
    _Pragma("unroll")                                                        \
    for (int mf = 0; mf < 4; ++mf)                                           \
        _Pragma("unroll")                                                    \
        for (int nf = 0; nf < 4; ++nf)                                       \
            acc[(qm) * 4 + mf][nf] = __builtin_amdgcn_mfma_f32_16x16x32_bf16(\
                ak[mf], bk[nf], acc[(qm) * 4 + mf][nf], 0, 0, 0);            \
    __builtin_amdgcn_s_setprio(0);                                           \
}

#define KTILE_BODY(t, cur, nxt) {                                            \
    const bool more_ = (t) + 1 < 16;                                         \
    /* phase 0: kh0/qm0 */                                                   \
    asm volatile("s_waitcnt vmcnt(4)" ::: "memory");                         \
    __builtin_amdgcn_s_barrier();                                            \
    if (more_) { STAGE((nxt), 0, 0, 0, (t)+1); STAGE((nxt), 0, 0, 1, (t)+1);}\
    RD_A((cur), 0, 0); RD_B((cur), 0);                                       \
    MAC16(0);                                                                \
    /* phase 1: kh0/qm1 */                                                   \
    if (more_) { STAGE((nxt), 1, 0, 0, (t)+1); STAGE((nxt), 1, 0, 1, (t)+1);}\
    RD_A((cur), 1, 0);                                                       \
    MAC16(1);                                                                \
    /* phase 2: kh1/qm0 */                                                   \
    if (more_) asm volatile("s_waitcnt vmcnt(4)" ::: "memory");              \
    else       asm volatile("s_waitcnt vmcnt(0)" ::: "memory");              \
    __builtin_amdgcn_s_barrier();                                            \
    if (more_) { STAGE((nxt), 0, 1, 0, (t)+1); STAGE((nxt), 0, 1, 1, (t)+1);}\
    RD_A((cur), 0, 1); RD_B((cur), 1);                                       \
    MAC16(0);                                                                \
    /* phase 3: kh1/qm1 */                                                   \
    if (more_) { STAGE((nxt), 1, 1, 0, (t)+1); STAGE((nxt), 1, 1, 1, (t)+1);}\
    RD_A((cur), 1, 1);                                                       \
    MAC16(1);                                                                \
}

__global__ void __launch_bounds__(512, 2) gemm8_qkv(Gemm8Args ga)
{
    extern __shared__ __align__(16) char smraw[];
    typedef short8 (*SmT)[2][2][256][4];     // [buf][A/B][kh][row][chunk]
    SmT sm = (SmT)smraw;

    // bijective XCD swizzle: nwg = 192, 192 % 8 == 0 -> 24 blocks per XCD
    const int bid0 = blockIdx.x;
    const int nid  = (bid0 & 7) * 24 + (bid0 >> 3);
    const int bm   = nid & 15;          // 16 M-tiles
    const int bn   = nid >> 4;          // 12 N-tiles
    const int m0   = bm * 256;
    const int seg  = bn >> 2;           // 0..2 -> Wq/Wk/Wv
    const int nw0  = (bn & 3) * 256;

    const bf16* __restrict__ A = ga.A;
    const bf16* __restrict__ W = ga.W[seg];
    bf16* __restrict__ Y = ga.Y[seg];
    const float scale = (seg == 0) ? ga.scale0 : 1.0f;

    const int tid  = threadIdx.x;
    const int lane = tid & 63;
    const int w    = tid >> 6;          // 0..7
    const int wm   = w >> 2;            // 0..1
    const int wn   = w & 3;             // 0..3

    const int srow = tid >> 2;          // 0..127 staging row within half
    const int scc  = (tid & 3) ^ ((srow >> 1) & 3);   // pre-swizzled chunk

    f32x4 acc[8][4] = {};
    short8 ak[4], bk[4];

    // prologue: stage K-tile 0 into buf0, consumption order
    STAGE(0, 0, 0, 0, 0); STAGE(0, 0, 0, 1, 0);   // A kh0
    STAGE(0, 1, 0, 0, 0); STAGE(0, 1, 0, 1, 0);   // B kh0
    STAGE(0, 0, 1, 0, 0); STAGE(0, 0, 1, 1, 0);   // A kh1
    STAGE(0, 1, 1, 0, 0); STAGE(0, 1, 1, 1, 0);   // B kh1

    #pragma unroll 1
    for (int t = 0; t < 16; t += 2) {
        KTILE_BODY(t,     0, 1);
        KTILE_BODY(t + 1, 1, 0);
    }

    // epilogue: C/D layout col=lane&15, row=(lane>>4)*4+r
    #pragma unroll
    for (int am = 0; am < 8; ++am) {
        #pragma unroll
        for (int nf = 0; nf < 4; ++nf) {
            const int row = m0 + wm * 128 + am * 16 + ((lane >> 4) << 2);
            const int col = nw0 + wn * 64 + nf * 16 + (lane & 15);
            #pragma unroll
            for (int r = 0; r < 4; ++r)
                Y[(size_t)(row + r) * 1024 + col] =
                    __float2bfloat16(acc[am][nf][r] * scale);
        }
    }
}

// ---------------------------------------------------------------------------
// Kernel 4: NT GEMM (m97 128^2 structure) for the output projection only.
// grid 32x8 = 256 blocks = 1/CU.  f32 output to d_out.
// ---------------------------------------------------------------------------
struct GemmArgs {
    const bf16* A;
    const bf16* W;
    float* Yf;
};

__global__ void __launch_bounds__(256) gemm_nt_f32(GemmArgs ga)
{
    __shared__ bf16 As[128 * 64];
    __shared__ bf16 Bs[128 * 64];

    const int m0 = blockIdx.x * 128;
    const int n0 = blockIdx.y * 128;
    const bf16* __restrict__ A = ga.A;
    const bf16* __restrict__ W = ga.W;

    const int t    = threadIdx.x;
    const int lane = t & 63;
    const int w    = t >> 6;
    const int wm   = w >> 1;
    const int wn   = w & 1;

    const int subrow = lane >> 3;
    const int kc     = lane & 7;

    f32x4 acc[4][4] = {};

    for (int kt = 0; kt < 16; ++kt) {
        const int k0 = kt * 64;
        if (kt) __syncthreads();
        #pragma unroll
        for (int i = 0; i < 4; ++i) {
            const int r0  = w * 32 + i * 8;
            const int row = r0 + subrow;
            const int kcs = kc ^ (subrow & 7);
            gld_lds16(A + (size_t)(m0 + row) * 1024 + k0 + kcs * 8, As + r0 * 64);
        }
        #pragma unroll
        for (int i = 0; i < 4; ++i) {
            const int r0  = w * 32 + i * 8;
            const int row = r0 + subrow;
            const int kcs = kc ^ (subrow & 7);
            gld_lds16(W + (size_t)(n0 + row) * 1024 + k0 + kcs * 8, Bs + r0 * 64);
        }
        __syncthreads();
        #pragma unroll
        for (int ks = 0; ks < 2; ++ks) {
            short8 af[4], bfv[4];
            #pragma unroll
            for (int mf = 0; mf < 4; ++mf) {
                const int row    = wm * 64 + mf * 16 + (lane & 15);
                const int kchunk = ks * 4 + (lane >> 4);
                const int pc     = kchunk ^ (row & 7);
                af[mf] = *reinterpret_cast<const short8*>(As + row * 64 + pc * 8);
            }
            #pragma unroll
            for (int nf = 0; nf < 4; ++nf) {
                const int row    = wn * 64 + nf * 16 + (lane & 15);
                const int kchunk = ks * 4 + (lane >> 4);
                const int pc     = kchunk ^ (row & 7);
                bfv[nf] = *reinterpret_cast<const short8*>(Bs + row * 64 + pc * 8);
            }
            #pragma unroll
            for (int mf = 0; mf < 4; ++mf)
                #pragma unroll
                for (int nf = 0; nf < 4; ++nf)
                    acc[mf][nf] = __builtin_amdgcn_mfma_f32_16x16x32_bf16(
                        af[mf], bfv[nf], acc[mf][nf], 0, 0, 0);
        }
    }

    #pragma unroll
    for (int mf = 0; mf < 4; ++mf) {
        #pragma unroll
        for (int nf = 0; nf < 4; ++nf) {
            const int row = m0 + wm * 64 + mf * 16 + ((lane >> 4) << 2);
            const int col = n0 + wn * 64 + nf * 16 + (lane & 15);
            #pragma unroll
            for (int r = 0; r < 4; ++r)
                ga.Yf[(size_t)(row + r) * 1024 + col] = acc[mf][nf][r];
        }
    }
}

// ---------------------------------------------------------------------------
// Kernel 3: K=32 neighbor attention — wave-synchronous, no LDS, no barriers
// (round-2 form: k gathered in-loop, v gathered after softmax).
//   lane = (hw<<4) | (half<<3) | c8 ;  h = wg*4+hw ; d-chunk = c8*8 (16B)
// ---------------------------------------------------------------------------
__global__ void __launch_bounds__(64) attn_knn(
    const bf16* __restrict__ qg, const bf16* __restrict__ kg,
    const bf16* __restrict__ vg, const int* __restrict__ idx,
    bf16* __restrict__ ao)
{
    const int wb = blockIdx.x;        // b*4 + wg  (fast dim -> XCD = wb)
    const int l  = blockIdx.y;
    const int b  = wb >> 2;
    const int wg = wb & 3;

    const int lane = threadIdx.x;     // 0..63
    const int hw   = lane >> 4;       // head within group
    const int h    = wg * 4 + hw;
    const int sl   = lane & 15;
    const int half = sl >> 3;
    const int c8   = sl & 7;

    const size_t rowq = (size_t)b * L_ + l;
    const unsigned short* kg16 = reinterpret_cast<const unsigned short*>(kg);
    const unsigned short* vg16 = reinterpret_cast<const unsigned short*>(vg);
    const size_t hoff = (size_t)h * DH_ + c8 * 8;

    int4 iv[4];
    #pragma unroll
    for (int i = 0; i < 4; ++i)
        iv[i] = reinterpret_cast<const int4*>(idx + l * K_ + half * 16)[i];

    u16x8 qv = *reinterpret_cast<const u16x8*>(
        reinterpret_cast<const unsigned short*>(qg) + rowq * C_ + hoff);
    float qf[8];
    #pragma unroll
    for (int e = 0; e < 8; ++e) qf[e] = bf2f(qv[e]);

    // ---- QK^T partial dots (16 independent 16B gathers) ----
    float s[16];
    #pragma unroll
    for (int jj = 0; jj < 16; ++jj) {
        const int4 q4 = iv[jj >> 2];
        const int row = (jj & 3) == 0 ? q4.x : (jj & 3) == 1 ? q4.y
                       : (jj & 3) == 2 ? q4.z : q4.w;
        const u16x8 kv = *reinterpret_cast<const u16x8*>(
            kg16 + ((size_t)b * L_ + row) * C_ + hoff);
        float acc = 0.f;
        #pragma unroll
        for (int e = 0; e < 8; ++e) acc += qf[e] * bf2f(kv[e]);
        s[jj] = acc;
    }

    #pragma unroll
    for (int jj = 0; jj < 16; ++jj) {
        float x = s[jj];
        x += __shfl_xor(x, 1, 16);
        x += __shfl_xor(x, 2, 16);
        x += __shfl_xor(x, 4, 16);
        s[jj] = x;
    }

    // ---- softmax in registers; 1/sum deferred to the store ----
    float m = s[0];
    #pragma unroll
    for (int jj = 1; jj < 16; ++jj) m = fmaxf(m, s[jj]);
    m = fmaxf(m, __shfl_xor(m, 8, 16));
    float ssum = 0.f;
    #pragma unroll
    for (int jj = 0; jj < 16; ++jj) { s[jj] = __expf(s[jj] - m); ssum += s[jj]; }
    ssum += __shfl_xor(ssum, 8, 16);
    const float inv = 1.0f / ssum;

    // ---- PV (16 independent 16B gathers) ----
    float acc[8] = {0.f, 0.f, 0.f, 0.f, 0.f, 0.f, 0.f, 0.f};
    #pragma unroll
    for (int jj = 0; jj < 16; ++jj) {
        const int4 q4 = iv[jj >> 2];
        const int row = (jj & 3) == 0 ? q4.x : (jj & 3) == 1 ? q4.y
                       : (jj & 3) == 2 ? q4.z : q4.w;
        const u16x8 vv = *reinterpret_cast<const u16x8*>(
            vg16 + ((size_t)b * L_ + row) * C_ + hoff);
        const float p = s[jj];
        #pragma unroll
        for (int e = 0; e < 8; ++e) acc[e] += p * bf2f(vv[e]);
    }
    #pragma unroll
    for (int e = 0; e < 8; ++e) acc[e] += __shfl_xor(acc[e], 8, 16);

    if (half == 0) {
        u16x8 o;
        #pragma unroll
        for (int e = 0; e < 8; ++e) o[e] = f2bf(acc[e] * inv);
        *reinterpret_cast<u16x8*>(ao + rowq * C_ + hoff) = o;
    }
}

// ---------------------------------------------------------------------------
// Launcher. Workspace layout (bytes):
//   xb 0 (8 MiB) | wqb 8M | wkb 10M | wvb 12M | wob 14M (2 MiB each)
//   q 16M | k 24M | v 32M | ao 40M  (8 MiB each)  -> total 48 MiB
// ---------------------------------------------------------------------------
extern "C" void kernel_launch(void* const* d_in, const int* in_sizes, int n_in,
                              void* d_out, int out_size, void* d_ws, size_t ws_size,
                              hipStream_t stream)
{
    const float* x  = (const float*)d_in[0];
    const int*   idx = (const int*)d_in[1];
    const float* Wq = (const float*)d_in[2];
    const float* Wk = (const float*)d_in[3];
    const float* Wv = (const float*)d_in[4];
    const float* Wo = (const float*)d_in[5];
    float* out = (float*)d_out;

    char* ws = (char*)d_ws;
    bf16* xb  = (bf16*)(ws + 0);
    bf16* wqb = (bf16*)(ws + 8388608);
    bf16* wkb = (bf16*)(ws + 10485760);
    bf16* wvb = (bf16*)(ws + 12582912);
    bf16* wob = (bf16*)(ws + 14680064);
    bf16* qb  = (bf16*)(ws + 16777216);
    bf16* kb  = (bf16*)(ws + 25165824);
    bf16* vb  = (bf16*)(ws + 33554432);
    bf16* ab  = (bf16*)(ws + 41943040);

    cvt_all<<<8192, 256, 0, stream>>>(x, Wq, Wk, Wv, Wo, xb, wqb, wkb, wvb, wob);

    Gemm8Args g1;
    g1.A = xb;
    g1.W[0] = wqb; g1.W[1] = wkb; g1.W[2] = wvb;
    g1.Y[0] = qb;  g1.Y[1] = kb;  g1.Y[2] = vb;
    g1.scale0 = 0.125f;   // 1/sqrt(Dh)
    gemm8_qkv<<<192, 512, 131072, stream>>>(g1);

    attn_knn<<<dim3(8, L_), 64, 0, stream>>>(qb, kb, vb, idx, ab);

    GemmArgs g2;
    g2.A = ab;
    g2.W = wob;
    g2.Yf = out;
    gemm_nt_f32<<<dim3(32, 8), 256, 0, stream>>>(g2);
}